// Round 1
// baseline (70.313 us; speedup 1.0000x reference)
//
#include <hip/hip_runtime.h>
#include <math.h>

#define TT 1024
#define DD 128

static constexpr float kNegInf = -1e9f;

// ---------------- K0a: wj[row] = dot(h[row,:], w) ----------------
__global__ __launch_bounds__(256) void k_wj(const float* __restrict__ h,
                                            const float* __restrict__ w,
                                            float* __restrict__ wj) {
  const int lane = threadIdx.x & 63;
  const int row  = (blockIdx.x << 2) + (threadIdx.x >> 6);  // 0..2047
  float a = h[(size_t)row * DD + lane] * w[lane] +
            h[(size_t)row * DD + 64 + lane] * w[64 + lane];
#pragma unroll
  for (int off = 32; off; off >>= 1) a += __shfl_xor(a, off);
  if (lane == 0) wj[row] = a;
}

// ------- K0b: hT4[(b*32+dq)*1024 + j] = float4(h[b][j][4dq..4dq+3]) -------
__global__ __launch_bounds__(256) void k_t(const float* __restrict__ h,
                                           float4* __restrict__ hT4) {
  __shared__ __align__(16) float tile[64 * 132];
  const int b  = blockIdx.x >> 4;
  const int jt = blockIdx.x & 15;
  const float4* src = (const float4*)(h + (size_t)(b * TT + jt * 64) * DD);
#pragma unroll
  for (int k = 0; k < 8; ++k) {
    int idx = k * 256 + threadIdx.x;     // 0..2047 float4 units (64 rows x 32)
    float4 v = src[idx];
    int j = idx >> 5, c = idx & 31;
    *((float4*)&tile[j * 132 + c * 4]) = v;
  }
  __syncthreads();
  const int j  = threadIdx.x & 63;
  const int dg = threadIdx.x >> 6;       // 0..3
#pragma unroll
  for (int k = 0; k < 8; ++k) {
    int dq = dg * 8 + k;                 // 0..31
    float4 v = *((const float4*)&tile[j * 132 + dq * 4]);
    hT4[(size_t)(b * 32 + dq) * TT + jt * 64 + j] = v;
  }
}

// ---------------- K2: S[b,i,j] = mask[j] ? -wj[j]*L1(h_i,h_j) : -1e9 ------
__global__ __launch_bounds__(256) void k_score(const float* __restrict__ h,
                                               const float4* __restrict__ hT4,
                                               const float* __restrict__ wj,
                                               const int* __restrict__ mk,
                                               float* __restrict__ S) {
  const int jt = blockIdx.x, it = blockIdx.y, b = blockIdx.z;
  const int wave = threadIdx.x >> 6, lane = threadIdx.x & 63;
  const int j = (jt << 6) + lane;
  const float wjv = wj[b * TT + j];
  const bool ok = (mk[b * TT + j] != 0);
  const float* hb = h + (size_t)b * TT * DD;
  const float4* hj = hT4 + (size_t)b * 32 * TT + j;
  const int i0 = (it << 6) + wave * 16;

#pragma unroll
  for (int g = 0; g < 2; ++g) {
    float acc[8];
#pragma unroll
    for (int r = 0; r < 8; ++r) acc[r] = 0.f;
    for (int dq = 0; dq < 32; ++dq) {
      const float4 hjv = hj[dq * TT];
#pragma unroll
      for (int r = 0; r < 8; ++r) {
        const float4 hiv =
            *((const float4*)&hb[(size_t)(i0 + g * 8 + r) * DD + dq * 4]);
        acc[r] += fabsf(hiv.x - hjv.x) + fabsf(hiv.y - hjv.y) +
                  fabsf(hiv.z - hjv.z) + fabsf(hiv.w - hjv.w);
      }
    }
#pragma unroll
    for (int r = 0; r < 8; ++r) {
      const int i = i0 + g * 8 + r;
      S[(size_t)(b * TT + i) * TT + j] = ok ? (-wjv * acc[r]) : kNegInf;
    }
  }
}

// ------------- K3: softmax over j + ctx = alpha @ h + concat --------------
// block = 512 threads, handles 8 consecutive global rows.
__global__ __launch_bounds__(512) void k_sm(const float* __restrict__ h,
                                            const float* __restrict__ S,
                                            float* __restrict__ out) {
  __shared__ __align__(16) float Pt[TT * 8];     // swizzled [j][r], 32 KB
  __shared__ float ctxp[4 * 8 * DD];             // [jq][r][d], 16 KB
  __shared__ float linv[8];

  const int b    = blockIdx.x >> 7;
  const int row0 = blockIdx.x << 3;              // global row base (0..2040)

  // ---- phase 1: one wave per row: max, exp, sum, write swizzled P ----
  {
    const int wv = threadIdx.x >> 6;             // row within block
    const int lane = threadIdx.x & 63;
    const int rowg = row0 + wv;
    const float4* Srow = (const float4*)(S + (size_t)rowg * TT);
    const float4 s0 = Srow[0 * 64 + lane];
    const float4 s1 = Srow[1 * 64 + lane];
    const float4 s2 = Srow[2 * 64 + lane];
    const float4 s3 = Srow[3 * 64 + lane];
    float m = fmaxf(fmaxf(fmaxf(s0.x, s0.y), fmaxf(s0.z, s0.w)),
                    fmaxf(fmaxf(s1.x, s1.y), fmaxf(s1.z, s1.w)));
    m = fmaxf(m, fmaxf(fmaxf(fmaxf(s2.x, s2.y), fmaxf(s2.z, s2.w)),
                       fmaxf(fmaxf(s3.x, s3.y), fmaxf(s3.z, s3.w))));
#pragma unroll
    for (int off = 32; off; off >>= 1) m = fmaxf(m, __shfl_xor(m, off));

    float p[16];
    p[0]  = expf(s0.x - m); p[1]  = expf(s0.y - m);
    p[2]  = expf(s0.z - m); p[3]  = expf(s0.w - m);
    p[4]  = expf(s1.x - m); p[5]  = expf(s1.y - m);
    p[6]  = expf(s1.z - m); p[7]  = expf(s1.w - m);
    p[8]  = expf(s2.x - m); p[9]  = expf(s2.y - m);
    p[10] = expf(s2.z - m); p[11] = expf(s2.w - m);
    p[12] = expf(s3.x - m); p[13] = expf(s3.y - m);
    p[14] = expf(s3.z - m); p[15] = expf(s3.w - m);

    float l = 0.f;
#pragma unroll
    for (int k = 0; k < 16; ++k) l += p[k];
#pragma unroll
    for (int off = 32; off; off >>= 1) l += __shfl_xor(l, off);

#pragma unroll
    for (int k = 0; k < 4; ++k) {
#pragma unroll
      for (int e = 0; e < 4; ++e) {
        const int j = k * 256 + lane * 4 + e;
        Pt[(j * 8 + wv) ^ (((j >> 3) & 7) << 2)] = p[k * 4 + e];
      }
    }
    if (lane == 0) linv[wv] = 1.f / l;
  }
  __syncthreads();

  // ---- phase 2: PV, lane-per-d, 4-way split over j ----
  const int d  = threadIdx.x & 127;
  const int jq = threadIdx.x >> 7;
  float c0 = 0, c1 = 0, c2 = 0, c3 = 0, c4 = 0, c5 = 0, c6 = 0, c7 = 0;
  const float* hb = h + (size_t)b * TT * DD;
  for (int jj = 0; jj < 256; ++jj) {
    const int j = (jq << 8) + jj;
    const int swz = ((j >> 3) & 7) << 2;
    const float4 pA = *(const float4*)&Pt[(j * 8) ^ swz];
    const float4 pB = *(const float4*)&Pt[(j * 8 + 4) ^ swz];
    const float hv = hb[(size_t)j * DD + d];
    c0 += pA.x * hv; c1 += pA.y * hv; c2 += pA.z * hv; c3 += pA.w * hv;
    c4 += pB.x * hv; c5 += pB.y * hv; c6 += pB.z * hv; c7 += pB.w * hv;
  }
  {
    float* cp = &ctxp[jq << 10];
    cp[0 * DD + d] = c0; cp[1 * DD + d] = c1;
    cp[2 * DD + d] = c2; cp[3 * DD + d] = c3;
    cp[4 * DD + d] = c4; cp[5 * DD + d] = c5;
    cp[6 * DD + d] = c6; cp[7 * DD + d] = c7;
  }
  __syncthreads();

  // ---- final: reduce partials, normalize, write concat(h, ctx) ----
#pragma unroll
  for (int k = 0; k < 2; ++k) {
    const int idx = threadIdx.x + k * 512;       // 0..1023
    const int r = idx >> 7, dd = idx & 127;
    const float sum = ctxp[0 * 1024 + r * DD + dd] +
                      ctxp[1 * 1024 + r * DD + dd] +
                      ctxp[2 * 1024 + r * DD + dd] +
                      ctxp[3 * 1024 + r * DD + dd];
    const int rowg = row0 + r;
    out[(size_t)rowg * 256 + dd]       = h[(size_t)rowg * DD + dd];
    out[(size_t)rowg * 256 + 128 + dd] = sum * linv[r];
  }
}

extern "C" void kernel_launch(void* const* d_in, const int* in_sizes, int n_in,
                              void* d_out, int out_size, void* d_ws, size_t ws_size,
                              hipStream_t stream) {
  const float* h  = (const float*)d_in[0];
  const int*   mk = (const int*)d_in[1];
  const float* w  = (const float*)d_in[2];
  float* out = (float*)d_out;

  char* ws = (char*)d_ws;
  float*  wj  = (float*)ws;                                   // 8 KB
  float4* hT4 = (float4*)(ws + 8192);                         // 1 MB
  float*  S   = (float*)(ws + 8192 + (size_t)2 * 32 * TT * 16);  // 8 MB

  hipLaunchKernelGGL(k_wj,    dim3(512),       dim3(256), 0, stream, h, w, wj);
  hipLaunchKernelGGL(k_t,     dim3(32),        dim3(256), 0, stream, h, hT4);
  hipLaunchKernelGGL(k_score, dim3(16, 16, 2), dim3(256), 0, stream, h, hT4, wj, mk, S);
  hipLaunchKernelGGL(k_sm,    dim3(256),       dim3(512), 0, stream, h, S, out);
}

// Round 2
// 51.222 us; speedup vs baseline: 1.3727x; 1.3727x over previous
//
#include <hip/hip_runtime.h>
#include <math.h>

#define TT 1024
#define DD 128
#define RB 4   // rows per fused block

static constexpr float kNegInf = -1e9f;

// ---- K0: wj = h.w ; swj = mask ? -wj : 0 ; bias = mask ? 0 : -1e9 ----
__global__ __launch_bounds__(256) void k_wj(const float* __restrict__ h,
                                            const float* __restrict__ w,
                                            const int* __restrict__ mk,
                                            float* __restrict__ swj,
                                            float* __restrict__ bias) {
  const int lane = threadIdx.x & 63;
  const int row  = (blockIdx.x << 2) + (threadIdx.x >> 6);  // 0..2047
  float a = h[(size_t)row * DD + lane] * w[lane] +
            h[(size_t)row * DD + 64 + lane] * w[64 + lane];
#pragma unroll
  for (int off = 32; off; off >>= 1) a += __shfl_xor(a, off);
  if (lane == 0) {
    const bool ok = (mk[row] != 0);
    swj[row]  = ok ? -a : 0.f;
    bias[row] = ok ? 0.f : kNegInf;
  }
}

// ---- K1: hT4[(b*32+dq)*1024 + j] = float4(h[b][j][4dq..4dq+3]) ----
__global__ __launch_bounds__(256) void k_t(const float* __restrict__ h,
                                           float4* __restrict__ hT4) {
  __shared__ __align__(16) float tile[64 * 132];
  const int b  = blockIdx.x >> 4;
  const int jt = blockIdx.x & 15;
  const float4* src = (const float4*)(h + (size_t)(b * TT + jt * 64) * DD);
#pragma unroll
  for (int k = 0; k < 8; ++k) {
    int idx = k * 256 + threadIdx.x;
    float4 v = src[idx];
    int j = idx >> 5, c = idx & 31;
    *((float4*)&tile[j * 132 + c * 4]) = v;
  }
  __syncthreads();
  const int j  = threadIdx.x & 63;
  const int dg = threadIdx.x >> 6;
#pragma unroll
  for (int k = 0; k < 8; ++k) {
    int dq = dg * 8 + k;
    float4 v = *((const float4*)&tile[j * 132 + dq * 4]);
    hT4[(size_t)(b * 32 + dq) * TT + jt * 64 + j] = v;
  }
}

// ---- K2: fused score -> softmax -> PV -> concat, 4 rows per block ----
__global__ __launch_bounds__(512) void k_fused(const float* __restrict__ h,
                                               const float4* __restrict__ hT4,
                                               const float* __restrict__ swj,
                                               const float* __restrict__ bias,
                                               float* __restrict__ out) {
  __shared__ __align__(16) float hi[RB * DD];        // 2 KB, block's i-rows
  __shared__ __align__(16) float Pt[TT * RB];        // 16 KB, P as [j][r]
  __shared__ __align__(16) float ctxp[4 * RB * DD];  // 8 KB, [q][r][d]
  __shared__ float wredm[8 * RB];                    // wave max partials
  __shared__ float wreds[8 * RB];                    // wave sum partials
  __shared__ float rsuminv[RB];

  const int tid  = threadIdx.x;
  const int row0 = blockIdx.x * RB;                  // global row base
  const int b    = row0 >> 10;
  const int lrow0 = row0 & 1023;
  const float* hb = h + (size_t)b * TT * DD;

  // stage the block's 4 i-rows into LDS (512 floats, one per thread)
  hi[tid] = hb[(size_t)lrow0 * DD + tid];
  __syncthreads();

  // ---------------- phase 1: scores (stay in registers) ----------------
  const float4* hjb = hT4 + (size_t)b * 32 * TT;
  float sc0[RB], sc1[RB];
  float pmax[RB];
#pragma unroll
  for (int p = 0; p < 2; ++p) {
    const int j = p * 512 + tid;
    float d0 = 0.f, d1 = 0.f, d2 = 0.f, d3 = 0.f;
#pragma unroll 8
    for (int dq = 0; dq < 32; ++dq) {
      const float4 hv = hjb[dq * TT + j];
      const float4 a0 = *(const float4*)&hi[0 * DD + dq * 4];
      const float4 a1 = *(const float4*)&hi[1 * DD + dq * 4];
      const float4 a2 = *(const float4*)&hi[2 * DD + dq * 4];
      const float4 a3 = *(const float4*)&hi[3 * DD + dq * 4];
      d0 += fabsf(a0.x - hv.x) + fabsf(a0.y - hv.y) +
            fabsf(a0.z - hv.z) + fabsf(a0.w - hv.w);
      d1 += fabsf(a1.x - hv.x) + fabsf(a1.y - hv.y) +
            fabsf(a1.z - hv.z) + fabsf(a1.w - hv.w);
      d2 += fabsf(a2.x - hv.x) + fabsf(a2.y - hv.y) +
            fabsf(a2.z - hv.z) + fabsf(a2.w - hv.w);
      d3 += fabsf(a3.x - hv.x) + fabsf(a3.y - hv.y) +
            fabsf(a3.z - hv.z) + fabsf(a3.w - hv.w);
    }
    const float sw = swj[b * TT + j];
    const float bv = bias[b * TT + j];
    float* sc = (p == 0) ? sc0 : sc1;
    sc[0] = fmaf(sw, d0, bv);
    sc[1] = fmaf(sw, d1, bv);
    sc[2] = fmaf(sw, d2, bv);
    sc[3] = fmaf(sw, d3, bv);
    if (p == 0) {
#pragma unroll
      for (int r = 0; r < RB; ++r) pmax[r] = sc[r];
    } else {
#pragma unroll
      for (int r = 0; r < RB; ++r) pmax[r] = fmaxf(pmax[r], sc[r]);
    }
  }

  // wave-level max reduce, then cross-wave via LDS
#pragma unroll
  for (int r = 0; r < RB; ++r)
#pragma unroll
    for (int off = 32; off; off >>= 1)
      pmax[r] = fmaxf(pmax[r], __shfl_xor(pmax[r], off));
  const int wv = tid >> 6;
  if ((tid & 63) == 0) {
#pragma unroll
    for (int r = 0; r < RB; ++r) wredm[wv * RB + r] = pmax[r];
  }
  __syncthreads();

  float m[RB];
#pragma unroll
  for (int r = 0; r < RB; ++r) {
    float mm = wredm[0 * RB + r];
#pragma unroll
    for (int w8 = 1; w8 < 8; ++w8) mm = fmaxf(mm, wredm[w8 * RB + r]);
    m[r] = mm;
  }

  // ---------------- phase 2: exp + sum + write P[j][r] ----------------
  float psum[RB];
  {
    float4 pv;
    pv.x = __expf(sc0[0] - m[0]);
    pv.y = __expf(sc0[1] - m[1]);
    pv.z = __expf(sc0[2] - m[2]);
    pv.w = __expf(sc0[3] - m[3]);
    *(float4*)&Pt[(size_t)tid * RB] = pv;
    psum[0] = pv.x; psum[1] = pv.y; psum[2] = pv.z; psum[3] = pv.w;
    pv.x = __expf(sc1[0] - m[0]);
    pv.y = __expf(sc1[1] - m[1]);
    pv.z = __expf(sc1[2] - m[2]);
    pv.w = __expf(sc1[3] - m[3]);
    *(float4*)&Pt[(size_t)(512 + tid) * RB] = pv;
    psum[0] += pv.x; psum[1] += pv.y; psum[2] += pv.z; psum[3] += pv.w;
  }
#pragma unroll
  for (int r = 0; r < RB; ++r)
#pragma unroll
    for (int off = 32; off; off >>= 1) psum[r] += __shfl_xor(psum[r], off);
  if ((tid & 63) == 0) {
#pragma unroll
    for (int r = 0; r < RB; ++r) wreds[wv * RB + r] = psum[r];
  }
  __syncthreads();

  if (tid < RB) {
    float s = 0.f;
#pragma unroll
    for (int w8 = 0; w8 < 8; ++w8) s += wreds[w8 * RB + tid];
    rsuminv[tid] = 1.f / s;
  }

  // ---------------- phase 3: PV (ctx partials over 4 j-quarters) -------
  const int q = tid >> 7;        // j-quarter
  const int d = tid & 127;       // feature dim
  float c0 = 0.f, c1 = 0.f, c2 = 0.f, c3 = 0.f;
#pragma unroll 8
  for (int jj = 0; jj < 256; ++jj) {
    const int j = (q << 8) + jj;
    const float4 pv = *(const float4*)&Pt[(size_t)j * RB];  // broadcast
    const float hv = hb[(size_t)j * DD + d];                // coalesced
    c0 = fmaf(pv.x, hv, c0);
    c1 = fmaf(pv.y, hv, c1);
    c2 = fmaf(pv.z, hv, c2);
    c3 = fmaf(pv.w, hv, c3);
  }
  ctxp[(q * RB + 0) * DD + d] = c0;
  ctxp[(q * RB + 1) * DD + d] = c1;
  ctxp[(q * RB + 2) * DD + d] = c2;
  ctxp[(q * RB + 3) * DD + d] = c3;
  __syncthreads();

  // ---------------- final: reduce partials, normalize, concat ----------
  {
    const int r  = tid >> 7;
    const int dd = tid & 127;
    const float s = ctxp[(0 * RB + r) * DD + dd] + ctxp[(1 * RB + r) * DD + dd] +
                    ctxp[(2 * RB + r) * DD + dd] + ctxp[(3 * RB + r) * DD + dd];
    const size_t rowg = (size_t)(row0 + r);
    out[rowg * 256 + dd]       = hi[r * DD + dd];
    out[rowg * 256 + 128 + dd] = s * rsuminv[r];
  }
}

extern "C" void kernel_launch(void* const* d_in, const int* in_sizes, int n_in,
                              void* d_out, int out_size, void* d_ws, size_t ws_size,
                              hipStream_t stream) {
  const float* h  = (const float*)d_in[0];
  const int*   mk = (const int*)d_in[1];
  const float* w  = (const float*)d_in[2];
  float* out = (float*)d_out;

  char* ws = (char*)d_ws;
  float*  swj  = (float*)ws;             // 8 KB
  float*  bias = (float*)(ws + 8192);    // 8 KB
  float4* hT4  = (float4*)(ws + 16384);  // 1 MB

  hipLaunchKernelGGL(k_wj,    dim3(512), dim3(256), 0, stream, h, w, mk, swj, bias);
  hipLaunchKernelGGL(k_t,     dim3(32),  dim3(256), 0, stream, h, hT4);
  hipLaunchKernelGGL(k_fused, dim3(512), dim3(512), 0, stream, h, hT4, swj, bias, out);
}

// Round 3
// 48.025 us; speedup vs baseline: 1.4641x; 1.0666x over previous
//
#include <hip/hip_runtime.h>
#include <math.h>

#define TT 1024
#define DD 128
#define RB 4   // rows per fused block

static constexpr float kNegInf = -1e9f;

__device__ __forceinline__ unsigned short f2bf(float x) {
  unsigned int u = __float_as_uint(x);
  u = (u + 0x7FFF + ((u >> 16) & 1)) >> 16;   // RNE
  return (unsigned short)u;
}
__device__ __forceinline__ float bf2f(unsigned short s) {
  return __uint_as_float(((unsigned int)s) << 16);
}

// ---- K0: wj = h.w ; swj = mask ? -wj : 0 ; bias = mask ? 0 : -1e9 ----
__global__ __launch_bounds__(256) void k_wj(const float* __restrict__ h,
                                            const float* __restrict__ w,
                                            const int* __restrict__ mk,
                                            float* __restrict__ swj,
                                            float* __restrict__ bias) {
  const int lane = threadIdx.x & 63;
  const int row  = (blockIdx.x << 2) + (threadIdx.x >> 6);  // 0..2047
  float a = h[(size_t)row * DD + lane] * w[lane] +
            h[(size_t)row * DD + 64 + lane] * w[64 + lane];
#pragma unroll
  for (int off = 32; off; off >>= 1) a += __shfl_xor(a, off);
  if (lane == 0) {
    const bool ok = (mk[row] != 0);
    swj[row]  = ok ? -a : 0.f;
    bias[row] = ok ? 0.f : kNegInf;
  }
}

// ---- K1: hT4[(b*32+dq)*1024 + j] = float4(h[b][j][4dq..]) ; hbf = bf16(h) --
__global__ __launch_bounds__(256) void k_t(const float* __restrict__ h,
                                           float4* __restrict__ hT4,
                                           ushort4* __restrict__ hbf) {
  __shared__ __align__(16) float tile[64 * 132];
  const int b  = blockIdx.x >> 4;
  const int jt = blockIdx.x & 15;
  const size_t base = (size_t)(b * TT + jt * 64) * 32;  // float4 units
  const float4* src = (const float4*)h + base;
#pragma unroll
  for (int k = 0; k < 8; ++k) {
    int idx = k * 256 + threadIdx.x;     // 0..2047
    float4 v = src[idx];
    int j = idx >> 5, c = idx & 31;
    *((float4*)&tile[j * 132 + c * 4]) = v;
    ushort4 bv;
    bv.x = f2bf(v.x); bv.y = f2bf(v.y); bv.z = f2bf(v.z); bv.w = f2bf(v.w);
    hbf[base + idx] = bv;
  }
  __syncthreads();
  const int j  = threadIdx.x & 63;
  const int dg = threadIdx.x >> 6;
#pragma unroll
  for (int k = 0; k < 8; ++k) {
    int dq = dg * 8 + k;
    float4 v = *((const float4*)&tile[j * 132 + dq * 4]);
    hT4[(size_t)(b * 32 + dq) * TT + jt * 64 + j] = v;
  }
}

// ---- K2: fused score -> softmax -> PV -> concat, 4 rows / 256 threads ----
__global__ __launch_bounds__(256) void k_fused(const float* __restrict__ h,
                                               const float4* __restrict__ hT4,
                                               const unsigned short* __restrict__ hbf,
                                               const float* __restrict__ swj,
                                               const float* __restrict__ bias,
                                               float* __restrict__ out) {
  __shared__ __align__(16) float hi[RB * DD];        // 2 KB
  __shared__ __align__(16) float Pt[TT * RB];        // 16 KB, [j][r]
  __shared__ __align__(16) float ctxp[8 * RB * DD];  // 16 KB, [g][r][d]
  __shared__ float wredm[4 * RB];
  __shared__ float wreds[4 * RB];
  __shared__ float rsuminv[RB];

  const int tid  = threadIdx.x;
  const int row0 = blockIdx.x * RB;
  const int b    = row0 >> 10;
  const int lrow0 = row0 & 1023;
  const float* hb = h + (size_t)b * TT * DD;

  // stage the 4 i-rows (512 floats)
  hi[tid]       = hb[(size_t)lrow0 * DD + tid];
  hi[tid + 256] = hb[(size_t)lrow0 * DD + tid + 256];
  __syncthreads();

  // ---------------- phase 1: distances, J=4 x RB=4 register block --------
  const float4* hjb = hT4 + (size_t)b * 32 * TT;
  const int jq = tid;                    // j = jq + 256*u
  float acc[4][RB];
#pragma unroll
  for (int u = 0; u < 4; ++u)
#pragma unroll
    for (int r = 0; r < RB; ++r) acc[u][r] = 0.f;

#pragma unroll 1
  for (int c = 0; c < 16; ++c) {         // 8 dims per chunk
    float4 A[RB][2];
#pragma unroll
    for (int r = 0; r < RB; ++r) {
      A[r][0] = *(const float4*)&hi[r * DD + c * 8];
      A[r][1] = *(const float4*)&hi[r * DD + c * 8 + 4];
    }
    float4 Bv[4][2];
#pragma unroll
    for (int u = 0; u < 4; ++u) {
      Bv[u][0] = hjb[(size_t)(c * 2 + 0) * TT + jq + u * 256];
      Bv[u][1] = hjb[(size_t)(c * 2 + 1) * TT + jq + u * 256];
    }
#pragma unroll
    for (int u = 0; u < 4; ++u)
#pragma unroll
      for (int r = 0; r < RB; ++r) {
        float s = acc[u][r];
        s += fabsf(A[r][0].x - Bv[u][0].x) + fabsf(A[r][0].y - Bv[u][0].y) +
             fabsf(A[r][0].z - Bv[u][0].z) + fabsf(A[r][0].w - Bv[u][0].w);
        s += fabsf(A[r][1].x - Bv[u][1].x) + fabsf(A[r][1].y - Bv[u][1].y) +
             fabsf(A[r][1].z - Bv[u][1].z) + fabsf(A[r][1].w - Bv[u][1].w);
        acc[u][r] = s;
      }
  }

  // scores
  float sc[4][RB];
#pragma unroll
  for (int u = 0; u < 4; ++u) {
    const float sw = swj[b * TT + jq + u * 256];
    const float bv = bias[b * TT + jq + u * 256];
#pragma unroll
    for (int r = 0; r < RB; ++r) sc[u][r] = fmaf(sw, acc[u][r], bv);
  }

  // row max: per-thread over u, wave shuffle, cross-wave LDS
  float pmax[RB];
#pragma unroll
  for (int r = 0; r < RB; ++r) {
    float mm = fmaxf(fmaxf(sc[0][r], sc[1][r]), fmaxf(sc[2][r], sc[3][r]));
#pragma unroll
    for (int off = 32; off; off >>= 1) mm = fmaxf(mm, __shfl_xor(mm, off));
    pmax[r] = mm;
  }
  const int wv = tid >> 6;
  if ((tid & 63) == 0) {
#pragma unroll
    for (int r = 0; r < RB; ++r) wredm[wv * RB + r] = pmax[r];
  }
  __syncthreads();
  float m[RB];
#pragma unroll
  for (int r = 0; r < RB; ++r)
    m[r] = fmaxf(fmaxf(wredm[0 * RB + r], wredm[1 * RB + r]),
                 fmaxf(wredm[2 * RB + r], wredm[3 * RB + r]));

  // exp + sum + write P[j][r]
  float psum[RB];
#pragma unroll
  for (int r = 0; r < RB; ++r) psum[r] = 0.f;
#pragma unroll
  for (int u = 0; u < 4; ++u) {
    float4 pv;
    pv.x = __expf(sc[u][0] - m[0]);
    pv.y = __expf(sc[u][1] - m[1]);
    pv.z = __expf(sc[u][2] - m[2]);
    pv.w = __expf(sc[u][3] - m[3]);
    *(float4*)&Pt[(size_t)(jq + u * 256) * RB] = pv;
    psum[0] += pv.x; psum[1] += pv.y; psum[2] += pv.z; psum[3] += pv.w;
  }
#pragma unroll
  for (int r = 0; r < RB; ++r)
#pragma unroll
    for (int off = 32; off; off >>= 1) psum[r] += __shfl_xor(psum[r], off);
  if ((tid & 63) == 0) {
#pragma unroll
    for (int r = 0; r < RB; ++r) wreds[wv * RB + r] = psum[r];
  }
  __syncthreads();
  if (tid < RB) {
    rsuminv[tid] = 1.f / (wreds[0 * RB + tid] + wreds[1 * RB + tid] +
                          wreds[2 * RB + tid] + wreds[3 * RB + tid]);
  }

  // ---------------- PV: thread = (4 dims) x (4 rows), 8-way j split ------
  const int dq = tid & 31;               // dim quad
  const int g  = tid >> 5;               // j-slice 0..7
  float cacc[RB][4];
#pragma unroll
  for (int r = 0; r < RB; ++r)
#pragma unroll
    for (int e = 0; e < 4; ++e) cacc[r][e] = 0.f;
  const unsigned short* hbf_b = hbf + (size_t)b * TT * DD;
#pragma unroll 4
  for (int jj = 0; jj < 128; ++jj) {
    const int j = (g << 7) + jj;
    const float4 pv = *(const float4*)&Pt[(size_t)j * RB];       // broadcast
    const ushort4 hv = *(const ushort4*)&hbf_b[(size_t)j * DD + dq * 4];
    const float h0 = bf2f(hv.x), h1 = bf2f(hv.y);
    const float h2 = bf2f(hv.z), h3 = bf2f(hv.w);
    cacc[0][0] = fmaf(pv.x, h0, cacc[0][0]);
    cacc[0][1] = fmaf(pv.x, h1, cacc[0][1]);
    cacc[0][2] = fmaf(pv.x, h2, cacc[0][2]);
    cacc[0][3] = fmaf(pv.x, h3, cacc[0][3]);
    cacc[1][0] = fmaf(pv.y, h0, cacc[1][0]);
    cacc[1][1] = fmaf(pv.y, h1, cacc[1][1]);
    cacc[1][2] = fmaf(pv.y, h2, cacc[1][2]);
    cacc[1][3] = fmaf(pv.y, h3, cacc[1][3]);
    cacc[2][0] = fmaf(pv.z, h0, cacc[2][0]);
    cacc[2][1] = fmaf(pv.z, h1, cacc[2][1]);
    cacc[2][2] = fmaf(pv.z, h2, cacc[2][2]);
    cacc[2][3] = fmaf(pv.z, h3, cacc[2][3]);
    cacc[3][0] = fmaf(pv.w, h0, cacc[3][0]);
    cacc[3][1] = fmaf(pv.w, h1, cacc[3][1]);
    cacc[3][2] = fmaf(pv.w, h2, cacc[3][2]);
    cacc[3][3] = fmaf(pv.w, h3, cacc[3][3]);
  }
#pragma unroll
  for (int r = 0; r < RB; ++r) {
    float4 cv = {cacc[r][0], cacc[r][1], cacc[r][2], cacc[r][3]};
    *(float4*)&ctxp[(size_t)(g * RB + r) * DD + dq * 4] = cv;
  }
  __syncthreads();

  // ---------------- final: reduce 8 partials, normalize, concat ----------
#pragma unroll
  for (int k = 0; k < 2; ++k) {
    const int idx = tid + k * 256;       // 0..511
    const int r  = idx >> 7;
    const int dd = idx & 127;
    float s = 0.f;
#pragma unroll
    for (int gg = 0; gg < 8; ++gg) s += ctxp[(size_t)(gg * RB + r) * DD + dd];
    const size_t rowg = (size_t)(row0 + r);
    out[rowg * 256 + dd]       = hi[r * DD + dd];
    out[rowg * 256 + 128 + dd] = s * rsuminv[r];
  }
}

extern "C" void kernel_launch(void* const* d_in, const int* in_sizes, int n_in,
                              void* d_out, int out_size, void* d_ws, size_t ws_size,
                              hipStream_t stream) {
  const float* h  = (const float*)d_in[0];
  const int*   mk = (const int*)d_in[1];
  const float* w  = (const float*)d_in[2];
  float* out = (float*)d_out;

  char* ws = (char*)d_ws;
  float*   swj  = (float*)ws;                        // 8 KB
  float*   bias = (float*)(ws + 8192);               // 8 KB
  float4*  hT4  = (float4*)(ws + 16384);             // 1 MB
  ushort4* hbf  = (ushort4*)(ws + 16384 + (size_t)2 * 32 * TT * 16);  // 512 KB

  hipLaunchKernelGGL(k_wj,    dim3(512), dim3(256), 0, stream, h, w, mk, swj, bias);
  hipLaunchKernelGGL(k_t,     dim3(32),  dim3(256), 0, stream, h, hT4, hbf);
  hipLaunchKernelGGL(k_fused, dim3(512), dim3(256), 0, stream, h, hT4,
                     (const unsigned short*)hbf, swj, bias, out);
}

// Round 4
// 45.522 us; speedup vs baseline: 1.5446x; 1.0550x over previous
//
#include <hip/hip_runtime.h>
#include <math.h>

#define TT 1024
#define DD 128
#define RB 4   // rows per fused block

static constexpr float kNegInf = -1e9f;

__device__ __forceinline__ unsigned short f2bf(float x) {
  unsigned int u = __float_as_uint(x);
  u = (u + 0x7FFF + ((u >> 16) & 1)) >> 16;   // RNE
  return (unsigned short)u;
}

// ---- K0: transpose + bf16 cast + wj/swj/bias, one block per 64 rows ----
__global__ __launch_bounds__(256) void k_prep(const float* __restrict__ h,
                                              const float* __restrict__ w,
                                              const int* __restrict__ mk,
                                              float4* __restrict__ hT4,
                                              ushort4* __restrict__ hbf,
                                              float* __restrict__ swj,
                                              float* __restrict__ bias) {
  __shared__ __align__(16) float tile[64 * 132];
  __shared__ float wred[64 * 4];
  const int b  = blockIdx.x >> 4;
  const int jt = blockIdx.x & 15;
  const size_t base = (size_t)(b * TT + jt * 64) * 32;  // float4 units
  const float4* src = (const float4*)h + base;
#pragma unroll
  for (int k = 0; k < 8; ++k) {
    int idx = k * 256 + threadIdx.x;     // 0..2047
    float4 v = src[idx];
    int j = idx >> 5, c = idx & 31;
    *((float4*)&tile[j * 132 + c * 4]) = v;
    ushort4 bv;
    bv.x = f2bf(v.x); bv.y = f2bf(v.y); bv.z = f2bf(v.z); bv.w = f2bf(v.w);
    hbf[base + idx] = bv;
  }
  __syncthreads();
  const int j  = threadIdx.x & 63;
  const int dg = threadIdx.x >> 6;       // 0..3
#pragma unroll
  for (int k = 0; k < 8; ++k) {
    int dq = dg * 8 + k;
    hT4[(size_t)(b * 32 + dq) * TT + jt * 64 + j] =
        *((const float4*)&tile[j * 132 + dq * 4]);
  }
  // wj partial: thread = (row j, dim-quarter dg)
  float p = 0.f;
#pragma unroll
  for (int e = 0; e < 32; e += 4) {
    float4 hv = *(const float4*)&tile[j * 132 + dg * 32 + e];
    float4 wv = *(const float4*)&w[dg * 32 + e];
    p += hv.x * wv.x + hv.y * wv.y + hv.z * wv.z + hv.w * wv.w;
  }
  wred[j * 4 + dg] = p;
  __syncthreads();
  if (threadIdx.x < 64) {
    const int row = b * TT + jt * 64 + threadIdx.x;
    const float a = wred[threadIdx.x * 4 + 0] + wred[threadIdx.x * 4 + 1] +
                    wred[threadIdx.x * 4 + 2] + wred[threadIdx.x * 4 + 3];
    const bool ok = (mk[row] != 0);
    swj[row]  = ok ? -a : 0.f;
    bias[row] = ok ? 0.f : kNegInf;
  }
}

// ---- K1: fused score -> softmax -> PV -> concat, 4 rows / 256 threads ----
__global__ __launch_bounds__(256) void k_fused(const float* __restrict__ h,
                                               const float4* __restrict__ hT4,
                                               const unsigned short* __restrict__ hbf,
                                               const float* __restrict__ swj,
                                               const float* __restrict__ bias,
                                               float* __restrict__ out) {
  __shared__ __align__(16) float Pt[TT * RB];        // 16 KB, [j][r]
  __shared__ __align__(16) float ctxp[8 * RB * DD];  // 16 KB, [g][r][d]
  __shared__ float wredm[4 * RB];
  __shared__ float wreds[4 * RB];
  __shared__ float rsuminv[RB];

  const int tid  = threadIdx.x;
  const int row0 = blockIdx.x * RB;
  const int b    = row0 >> 10;
  const int lrow0 = row0 & 1023;
  const float* hb = h + (size_t)b * TT * DD;
  const float* hA = hb + (size_t)lrow0 * DD;   // block-uniform A base

  // ---------------- phase 1: distances, J=4 x RB=4, double-buffered ------
  const float4* hjb = hT4 + (size_t)b * 32 * TT;
  const int jq = tid;                    // j = jq + 256*u

  float acc[4][RB];
#pragma unroll
  for (int u = 0; u < 4; ++u)
#pragma unroll
    for (int r = 0; r < RB; ++r) acc[u][r] = 0.f;

  auto loadB = [&](float4 (&B)[4][2], int c) {
#pragma unroll
    for (int u = 0; u < 4; ++u)
#pragma unroll
      for (int k = 0; k < 2; ++k)
        B[u][k] = hjb[(size_t)(c * 2 + k) * TT + jq + u * 256];
  };
  auto loadA = [&](float4 (&A)[RB][2], int c) {
#pragma unroll
    for (int r = 0; r < RB; ++r)
#pragma unroll
      for (int k = 0; k < 2; ++k)
        A[r][k] = *(const float4*)&hA[r * DD + c * 8 + k * 4];
  };
  auto comp = [&](float4 (&A)[RB][2], float4 (&B)[4][2]) {
#pragma unroll
    for (int u = 0; u < 4; ++u)
#pragma unroll
      for (int r = 0; r < RB; ++r) {
        float s = acc[u][r];
        s += fabsf(A[r][0].x - B[u][0].x) + fabsf(A[r][0].y - B[u][0].y) +
             fabsf(A[r][0].z - B[u][0].z) + fabsf(A[r][0].w - B[u][0].w);
        s += fabsf(A[r][1].x - B[u][1].x) + fabsf(A[r][1].y - B[u][1].y) +
             fabsf(A[r][1].z - B[u][1].z) + fabsf(A[r][1].w - B[u][1].w);
        acc[u][r] = s;
      }
  };

  {
    float4 B0[4][2], B1[4][2], A0[RB][2], A1[RB][2];
    loadB(B0, 0); loadA(A0, 0);
#pragma unroll 1
    for (int c = 0; c < 16; c += 2) {
      loadB(B1, c + 1); loadA(A1, c + 1);
      comp(A0, B0);
      if (c < 14) { loadB(B0, c + 2); loadA(A0, c + 2); }
      comp(A1, B1);
    }
  }

  // scores
  float sc[4][RB];
#pragma unroll
  for (int u = 0; u < 4; ++u) {
    const float sw = swj[b * TT + jq + u * 256];
    const float bv = bias[b * TT + jq + u * 256];
#pragma unroll
    for (int r = 0; r < RB; ++r) sc[u][r] = fmaf(sw, acc[u][r], bv);
  }

  // row max: per-thread over u, wave shuffle, cross-wave LDS
  float pmax[RB];
#pragma unroll
  for (int r = 0; r < RB; ++r) {
    float mm = fmaxf(fmaxf(sc[0][r], sc[1][r]), fmaxf(sc[2][r], sc[3][r]));
#pragma unroll
    for (int off = 32; off; off >>= 1) mm = fmaxf(mm, __shfl_xor(mm, off));
    pmax[r] = mm;
  }
  const int wv = tid >> 6;
  if ((tid & 63) == 0) {
#pragma unroll
    for (int r = 0; r < RB; ++r) wredm[wv * RB + r] = pmax[r];
  }
  __syncthreads();
  float m[RB];
#pragma unroll
  for (int r = 0; r < RB; ++r)
    m[r] = fmaxf(fmaxf(wredm[0 * RB + r], wredm[1 * RB + r]),
                 fmaxf(wredm[2 * RB + r], wredm[3 * RB + r]));

  // exp + sum + write P[j][r]
  float psum[RB];
#pragma unroll
  for (int r = 0; r < RB; ++r) psum[r] = 0.f;
#pragma unroll
  for (int u = 0; u < 4; ++u) {
    float4 pv;
    pv.x = __expf(sc[u][0] - m[0]);
    pv.y = __expf(sc[u][1] - m[1]);
    pv.z = __expf(sc[u][2] - m[2]);
    pv.w = __expf(sc[u][3] - m[3]);
    *(float4*)&Pt[(size_t)(jq + u * 256) * RB] = pv;
    psum[0] += pv.x; psum[1] += pv.y; psum[2] += pv.z; psum[3] += pv.w;
  }
#pragma unroll
  for (int r = 0; r < RB; ++r)
#pragma unroll
    for (int off = 32; off; off >>= 1) psum[r] += __shfl_xor(psum[r], off);
  if ((tid & 63) == 0) {
#pragma unroll
    for (int r = 0; r < RB; ++r) wreds[wv * RB + r] = psum[r];
  }
  __syncthreads();
  if (tid < RB) {
    rsuminv[tid] = 1.f / (wreds[0 * RB + tid] + wreds[1 * RB + tid] +
                          wreds[2 * RB + tid] + wreds[3 * RB + tid]);
  }

  // ---------------- PV: thread = (4 dims) x (4 rows), 8-way j split ------
  const int dq = tid & 31;               // dim quad
  const int g  = tid >> 5;               // j-slice 0..7
  const int jb = g << 7;
  float cacc[RB][4];
#pragma unroll
  for (int r = 0; r < RB; ++r)
#pragma unroll
    for (int e = 0; e < 4; ++e) cacc[r][e] = 0.f;
  const unsigned short* hbf_b = hbf + (size_t)b * TT * DD;

  auto loadPV = [&](float4 (&P)[4], uint2 (&V)[4], int jbase) {
#pragma unroll
    for (int t = 0; t < 4; ++t) {
      P[t] = *(const float4*)&Pt[(size_t)(jbase + t) * RB];
      V[t] = *(const uint2*)&hbf_b[(size_t)(jbase + t) * DD + dq * 4];
    }
  };
  auto pvcomp = [&](float4 (&P)[4], uint2 (&V)[4]) {
#pragma unroll
    for (int t = 0; t < 4; ++t) {
      const float h0 = __uint_as_float(V[t].x << 16);
      const float h1 = __uint_as_float(V[t].x & 0xFFFF0000u);
      const float h2 = __uint_as_float(V[t].y << 16);
      const float h3 = __uint_as_float(V[t].y & 0xFFFF0000u);
      cacc[0][0] = fmaf(P[t].x, h0, cacc[0][0]);
      cacc[0][1] = fmaf(P[t].x, h1, cacc[0][1]);
      cacc[0][2] = fmaf(P[t].x, h2, cacc[0][2]);
      cacc[0][3] = fmaf(P[t].x, h3, cacc[0][3]);
      cacc[1][0] = fmaf(P[t].y, h0, cacc[1][0]);
      cacc[1][1] = fmaf(P[t].y, h1, cacc[1][1]);
      cacc[1][2] = fmaf(P[t].y, h2, cacc[1][2]);
      cacc[1][3] = fmaf(P[t].y, h3, cacc[1][3]);
      cacc[2][0] = fmaf(P[t].z, h0, cacc[2][0]);
      cacc[2][1] = fmaf(P[t].z, h1, cacc[2][1]);
      cacc[2][2] = fmaf(P[t].z, h2, cacc[2][2]);
      cacc[2][3] = fmaf(P[t].z, h3, cacc[2][3]);
      cacc[3][0] = fmaf(P[t].w, h0, cacc[3][0]);
      cacc[3][1] = fmaf(P[t].w, h1, cacc[3][1]);
      cacc[3][2] = fmaf(P[t].w, h2, cacc[3][2]);
      cacc[3][3] = fmaf(P[t].w, h3, cacc[3][3]);
    }
  };

  {
    float4 P0[4], P1[4]; uint2 V0[4], V1[4];
    loadPV(P0, V0, jb);
#pragma unroll 1
    for (int it = 0; it < 16; ++it) {
      loadPV(P1, V1, jb + it * 8 + 4);
      pvcomp(P0, V0);
      if (it < 15) loadPV(P0, V0, jb + it * 8 + 8);
      pvcomp(P1, V1);
    }
  }

#pragma unroll
  for (int r = 0; r < RB; ++r) {
    float4 cv = {cacc[r][0], cacc[r][1], cacc[r][2], cacc[r][3]};
    *(float4*)&ctxp[(size_t)(g * RB + r) * DD + dq * 4] = cv;
  }
  __syncthreads();

  // ---------------- final: reduce 8 partials, normalize, concat ----------
#pragma unroll
  for (int k = 0; k < 2; ++k) {
    const int idx = tid + k * 256;       // 0..511
    const int r  = idx >> 7;
    const int dd = idx & 127;
    float s = 0.f;
#pragma unroll
    for (int gg = 0; gg < 8; ++gg) s += ctxp[(size_t)(gg * RB + r) * DD + dd];
    const size_t rowg = (size_t)(row0 + r);
    out[rowg * 256 + dd]       = hA[r * DD + dd];
    out[rowg * 256 + 128 + dd] = s * rsuminv[r];
  }
}

extern "C" void kernel_launch(void* const* d_in, const int* in_sizes, int n_in,
                              void* d_out, int out_size, void* d_ws, size_t ws_size,
                              hipStream_t stream) {
  const float* h  = (const float*)d_in[0];
  const int*   mk = (const int*)d_in[1];
  const float* w  = (const float*)d_in[2];
  float* out = (float*)d_out;

  char* ws = (char*)d_ws;
  float*   swj  = (float*)ws;                        // 8 KB
  float*   bias = (float*)(ws + 8192);               // 8 KB
  float4*  hT4  = (float4*)(ws + 16384);             // 1 MB
  ushort4* hbf  = (ushort4*)(ws + 16384 + (size_t)2 * 32 * TT * 16);  // 512 KB

  hipLaunchKernelGGL(k_prep,  dim3(32),  dim3(256), 0, stream,
                     h, w, mk, hT4, hbf, swj, bias);
  hipLaunchKernelGGL(k_fused, dim3(512), dim3(256), 0, stream, h, hT4,
                     (const unsigned short*)hbf, swj, bias, out);
}